// Round 1
// baseline (612.014 us; speedup 1.0000x reference)
//
#include <hip/hip_runtime.h>
#include <hip/hip_bf16.h>
#include <math.h>

#define NB_DIGITS 2
#define NUMS 100
#define SUMS 199
#define BATCH 4096

// One workgroup = one batch element = 4 digit images, fully fused:
// conv1+pool+relu -> conv2+pool+relu -> fc1 -> fc2 -> fc3 -> log_softmax -> circuit.
// All intermediates live in LDS (~44 KB/WG -> 3 WG/CU).
__global__ __launch_bounds__(256) void lenet_circuit_kernel(
    const float* __restrict__ images,
    const float* __restrict__ c1w, const float* __restrict__ c1b,
    const float* __restrict__ c2w, const float* __restrict__ c2b,
    const float* __restrict__ f1w, const float* __restrict__ f1b,
    const float* __restrict__ f2w, const float* __restrict__ f2b,
    const float* __restrict__ f3w, const float* __restrict__ f3b,
    float* __restrict__ out)
{
    __shared__ float s_img[4][28 * 28];     // 12544 B
    __shared__ float s_w1[6 * 25];          // 600 B
    __shared__ float s_b1[6];
    __shared__ float s_w2[16 * 6 * 25];     // 9600 B
    __shared__ float s_b2[16];
    __shared__ float s_p1[4][6][12 * 12];   // 13824 B  post conv1+pool+relu
    __shared__ float s_p2[4][256];          // 4096 B   post conv2+pool+relu (flattened)
    __shared__ float s_f1[4][120];          // 1920 B
    __shared__ float s_f2[4][84];           // 1344 B
    __shared__ float s_lp[4][10];           // logits -> log-probs
    __shared__ float s_lp1[NUMS];           // log P(n1=k)
    __shared__ float s_lp2[NUMS];           // log P(n2=k)

    const int t = threadIdx.x;
    const int b = blockIdx.x;

    // ---- stage images + conv weights into LDS ----
    const float* gimg = images + (size_t)b * 4 * 784;
    for (int i = t; i < 4 * 784; i += 256) s_img[i / 784][i % 784] = gimg[i];
    for (int i = t; i < 150;  i += 256) s_w1[i] = c1w[i];
    for (int i = t; i < 2400; i += 256) s_w2[i] = c2w[i];
    if (t < 6)  s_b1[t] = c1b[t];
    if (t < 16) s_b2[t] = c2b[t];
    __syncthreads();

    // ---- conv1 (5x5, 1->6) + maxpool2 + relu : 4 imgs x 6 oc x 12x12 pooled outs ----
    for (int task = t; task < 4 * 6 * 144; task += 256) {
        const int px = task % 12;
        const int py = (task / 12) % 12;
        const int oc = (task / 144) % 6;
        const int im = task / 864;

        float w[25];
        #pragma unroll
        for (int k = 0; k < 25; k++) w[k] = s_w1[oc * 25 + k];

        // 6x6 input window covers all 4 pre-pool positions
        float win[6][6];
        const int y0 = 2 * py, x0 = 2 * px;
        #pragma unroll
        for (int r = 0; r < 6; r++)
            #pragma unroll
            for (int c = 0; c < 6; c++)
                win[r][c] = s_img[im][(y0 + r) * 28 + (x0 + c)];

        const float bias = s_b1[oc];
        float mx = -INFINITY;
        #pragma unroll
        for (int dy = 0; dy < 2; dy++) {
            #pragma unroll
            for (int dx = 0; dx < 2; dx++) {
                float acc = bias;
                #pragma unroll
                for (int ky = 0; ky < 5; ky++)
                    #pragma unroll
                    for (int kx = 0; kx < 5; kx++)
                        acc += win[dy + ky][dx + kx] * w[ky * 5 + kx];
                mx = fmaxf(mx, acc);
            }
        }
        s_p1[im][oc][py * 12 + px] = fmaxf(mx, 0.f);
    }
    __syncthreads();

    // ---- conv2 (5x5, 6->16) + maxpool2 + relu : 4 x 16 x 4x4 pooled outs ----
    for (int task = t; task < 4 * 16 * 16; task += 256) {
        const int px = task % 4;
        const int py = (task / 4) % 4;
        const int oc = (task / 16) % 16;
        const int im = task / 256;

        const float bias = s_b2[oc];
        float acc[4] = {bias, bias, bias, bias};
        const int y0 = 2 * py, x0 = 2 * px;

        for (int ic = 0; ic < 6; ic++) {
            float w[25];
            #pragma unroll
            for (int k = 0; k < 25; k++) w[k] = s_w2[(oc * 6 + ic) * 25 + k];
            float win[6][6];
            #pragma unroll
            for (int r = 0; r < 6; r++)
                #pragma unroll
                for (int c = 0; c < 6; c++)
                    win[r][c] = s_p1[im][ic][(y0 + r) * 12 + (x0 + c)];
            #pragma unroll
            for (int dy = 0; dy < 2; dy++)
                #pragma unroll
                for (int dx = 0; dx < 2; dx++) {
                    float a = acc[dy * 2 + dx];
                    #pragma unroll
                    for (int ky = 0; ky < 5; ky++)
                        #pragma unroll
                        for (int kx = 0; kx < 5; kx++)
                            a += win[dy + ky][dx + kx] * w[ky * 5 + kx];
                    acc[dy * 2 + dx] = a;
                }
        }
        float mx = fmaxf(fmaxf(acc[0], acc[1]), fmaxf(acc[2], acc[3]));
        // flatten index (NCHW): oc*16 + py*4 + px
        s_p2[im][oc * 16 + py * 4 + px] = fmaxf(mx, 0.f);
    }
    __syncthreads();

    // ---- fc1 (256 -> 120) + relu : 480 dots of len 256 ----
    for (int task = t; task < 4 * 120; task += 256) {
        const int o  = task % 120;
        const int im = task / 120;
        const float4* wr = (const float4*)(f1w + (size_t)o * 256);
        const float4* xr = (const float4*)&s_p2[im][0];
        float acc = f1b[o];
        #pragma unroll 8
        for (int k = 0; k < 64; k++) {
            float4 w4 = wr[k], x4 = xr[k];
            acc += w4.x * x4.x + w4.y * x4.y + w4.z * x4.z + w4.w * x4.w;
        }
        s_f1[im][o] = fmaxf(acc, 0.f);
    }
    __syncthreads();

    // ---- fc2 (120 -> 84) + relu ----
    for (int task = t; task < 4 * 84; task += 256) {
        const int o  = task % 84;
        const int im = task / 84;
        const float* wr = f2w + (size_t)o * 120;
        float acc = f2b[o];
        #pragma unroll 8
        for (int k = 0; k < 120; k++) acc += wr[k] * s_f1[im][k];
        s_f2[im][o] = fmaxf(acc, 0.f);
    }
    __syncthreads();

    // ---- fc3 (84 -> 10), raw logits ----
    for (int task = t; task < 4 * 10; task += 256) {
        const int o  = task % 10;
        const int im = task / 10;
        const float* wr = f3w + (size_t)o * 84;
        float acc = f3b[o];
        #pragma unroll
        for (int k = 0; k < 84; k++) acc += wr[k] * s_f2[im][k];
        s_lp[im][o] = acc;
    }
    __syncthreads();

    // ---- log_softmax per image (stable) ----
    if (t < 4) {
        float mx = -INFINITY;
        #pragma unroll
        for (int i = 0; i < 10; i++) mx = fmaxf(mx, s_lp[t][i]);
        float sum = 0.f;
        #pragma unroll
        for (int i = 0; i < 10; i++) sum += expf(s_lp[t][i] - mx);
        const float lse = mx + logf(sum);
        #pragma unroll
        for (int i = 0; i < 10; i++) s_lp[t][i] -= lse;
    }
    __syncthreads();

    // ---- circuit: lp1[k]=lp[0][k/10]+lp[1][k%10], lp2[k]=lp[2][k/10]+lp[3][k%10] ----
    if (t < NUMS) {
        s_lp1[t] = s_lp[0][t / 10] + s_lp[1][t % 10];
    } else if (t < 2 * NUMS) {
        const int k = t - NUMS;
        s_lp2[k] = s_lp[2][k / 10] + s_lp[3][k % 10];
    }
    __syncthreads();

    // ---- per-segment exact logsumexp over {(i,j): i+j=s} ----
    if (t < SUMS) {
        const int s   = t;
        const int ilo = (s > 99) ? (s - 99) : 0;
        const int ihi = (s < 99) ? s : 99;
        float m = -INFINITY;
        for (int i = ilo; i <= ihi; i++) m = fmaxf(m, s_lp1[i] + s_lp2[s - i]);
        float sum = 0.f;
        for (int i = ilo; i <= ihi; i++) sum += expf(s_lp1[i] + s_lp2[s - i] - m);
        out[(size_t)b * SUMS + s] = logf(sum) + m;
    }
}

extern "C" void kernel_launch(void* const* d_in, const int* in_sizes, int n_in,
                              void* d_out, int out_size, void* d_ws, size_t ws_size,
                              hipStream_t stream) {
    const float* images = (const float*)d_in[0];
    const float* c1w = (const float*)d_in[1];
    const float* c1b = (const float*)d_in[2];
    const float* c2w = (const float*)d_in[3];
    const float* c2b = (const float*)d_in[4];
    const float* f1w = (const float*)d_in[5];
    const float* f1b = (const float*)d_in[6];
    const float* f2w = (const float*)d_in[7];
    const float* f2b = (const float*)d_in[8];
    const float* f3w = (const float*)d_in[9];
    const float* f3b = (const float*)d_in[10];
    float* out = (float*)d_out;

    lenet_circuit_kernel<<<BATCH, 256, 0, stream>>>(
        images, c1w, c1b, c2w, c2b, f1w, f1b, f2w, f2b, f3w, f3b, out);
}

// Round 2
// 442.531 us; speedup vs baseline: 1.3830x; 1.3830x over previous
//
#include <hip/hip_runtime.h>
#include <hip/hip_bf16.h>
#include <math.h>

#define NB_DIGITS 2
#define NUMS 100
#define SUMS 199
#define BATCH 4096

// One workgroup = one batch element = 4 digit images, fully fused.
// Register-tiled convs: each thread owns an output row (conv1) / pooled row
// (conv2) and keeps the input window + weights in VGPRs; all LDS reads are
// 16B-aligned so the compiler merges them into ds_read_b128.
// LDS ~37 KB -> 4 blocks/CU.
__global__ __launch_bounds__(256) void lenet_circuit_kernel(
    const float* __restrict__ images,
    const float* __restrict__ c1w, const float* __restrict__ c1b,
    const float* __restrict__ c2w, const float* __restrict__ c2b,
    const float* __restrict__ f1w, const float* __restrict__ f1b,
    const float* __restrict__ f2w, const float* __restrict__ f2b,
    const float* __restrict__ f3w, const float* __restrict__ f3b,
    float* __restrict__ out)
{
    // Reused region: images (phase A/B), then post-conv2 activations onward.
    __shared__ __align__(16) float s_reuse[3136];          // 12544 B
    __shared__ __align__(16) float s_p1[4][6][144];        // 13824 B
    __shared__ __align__(16) float s_w1p[6 * 28];          // 672 B (rows padded to 28)
    __shared__ __align__(16) float s_w2p[16 * 6 * 28];     // 10752 B (rows padded to 28)
    __shared__ float s_b1[6];
    __shared__ float s_b2[16];

    float (*s_img)[784] = (float (*)[784])s_reuse;          // phases A,B
    float (*s_p2)[256]  = (float (*)[256])s_reuse;          // 1024 floats
    float (*s_f1)[120]  = (float (*)[120])(s_reuse + 1024); // 480
    float (*s_f2)[84]   = (float (*)[84])(s_reuse + 1504);  // 336
    float (*s_lp)[10]   = (float (*)[10])(s_reuse + 1840);  // 40
    float *s_lp1 = s_reuse + 1880;                          // 100
    float *s_lp2 = s_reuse + 1980;                          // 100 (total 2080 <= 3136)

    const int t = threadIdx.x;
    const int b = blockIdx.x;

    // ---- stage images (float4) + padded conv weights ----
    {
        const float4* g = (const float4*)(images + (size_t)b * 3136);
        float4* s4 = (float4*)s_reuse;
        for (int i = t; i < 784; i += 256) s4[i] = g[i];
        for (int i = t; i < 6 * 28; i += 256) {
            const int row = i / 28, col = i % 28;
            s_w1p[i] = (col < 25) ? c1w[row * 25 + col] : 0.f;
        }
        for (int i = t; i < 16 * 6 * 28; i += 256) {
            const int row = i / 28, col = i % 28;
            s_w2p[i] = (col < 25) ? c2w[row * 25 + col] : 0.f;
        }
        if (t < 6)  s_b1[t] = c1b[t];
        else if (t >= 32 && t < 48) s_b2[t - 32] = c2b[t - 32];
    }
    __syncthreads();

    // ---- conv1 (5x5,1->6)+pool+relu: task=(im,oc,py), 288 tasks, 12 outs each ----
    for (int task = t; task < 288; task += 256) {
        const int py = task % 12;
        const int oc = (task / 12) % 6;
        const int im = task / 72;
        const int y0 = 2 * py;

        float w[25];
        #pragma unroll
        for (int k = 0; k < 25; ++k) w[k] = s_w1p[oc * 28 + k];
        const float bias = s_b1[oc];

        for (int q = 0; q < 6; ++q) {          // pair of pooled outputs
            const int x0 = 4 * q;
            float win[6][8];                    // 16B-aligned rows -> 2x b128 each
            #pragma unroll
            for (int r = 0; r < 6; ++r)
                #pragma unroll
                for (int c = 0; c < 8; ++c)
                    win[r][c] = s_img[im][(y0 + r) * 28 + x0 + c];
            #pragma unroll
            for (int h = 0; h < 2; ++h) {
                float mx = -INFINITY;
                #pragma unroll
                for (int dy = 0; dy < 2; ++dy)
                    #pragma unroll
                    for (int dx = 0; dx < 2; ++dx) {
                        float a = bias;
                        #pragma unroll
                        for (int ky = 0; ky < 5; ++ky)
                            #pragma unroll
                            for (int kx = 0; kx < 5; ++kx)
                                a += win[dy + ky][2 * h + dx + kx] * w[ky * 5 + kx];
                        mx = fmaxf(mx, a);
                    }
                s_p1[im][oc][py * 12 + 2 * q + h] = fmaxf(mx, 0.f);
            }
        }
    }
    __syncthreads();

    // ---- conv2 (5x5,6->16)+pool+relu: task=(im,oc,py), exactly 256 tasks ----
    {
        const int py = t % 4;
        const int oc = (t / 4) % 16;
        const int im = t / 64;
        const int y0 = 2 * py;

        const float bias = s_b2[oc];
        float acc[2][8];                        // pre-pool rows 2py,2py+1 x cols 0..7
        #pragma unroll
        for (int a = 0; a < 2; ++a)
            #pragma unroll
            for (int x = 0; x < 8; ++x) acc[a][x] = bias;

        #pragma unroll 1
        for (int ic = 0; ic < 6; ++ic) {
            float w[25];
            #pragma unroll
            for (int k = 0; k < 25; ++k) w[k] = s_w2p[(oc * 6 + ic) * 28 + k];
            float win[6][12];                   // rows 16B-aligned -> 3x b128 each
            #pragma unroll
            for (int r = 0; r < 6; ++r)
                #pragma unroll
                for (int c = 0; c < 12; ++c)
                    win[r][c] = s_p1[im][ic][(y0 + r) * 12 + c];
            #pragma unroll
            for (int a = 0; a < 2; ++a)
                #pragma unroll
                for (int x = 0; x < 8; ++x) {
                    float s = acc[a][x];
                    #pragma unroll
                    for (int ky = 0; ky < 5; ++ky)
                        #pragma unroll
                        for (int kx = 0; kx < 5; ++kx)
                            s += win[a + ky][x + kx] * w[ky * 5 + kx];
                    acc[a][x] = s;
                }
        }
        #pragma unroll
        for (int px = 0; px < 4; ++px) {
            const float mx = fmaxf(fmaxf(acc[0][2 * px], acc[0][2 * px + 1]),
                                   fmaxf(acc[1][2 * px], acc[1][2 * px + 1]));
            s_p2[im][oc * 16 + py * 4 + px] = fmaxf(mx, 0.f);
        }
    }
    __syncthreads();

    // ---- fc1 (256->120)+relu: task=(o, im-pair), 240 tasks, weights read once/2 imgs ----
    if (t < 240) {
        const int o = t % 120;
        const int im0 = (t / 120) * 2, im1 = im0 + 1;
        const float4* wr = (const float4*)(f1w + (size_t)o * 256);
        const float4* x0 = (const float4*)s_p2[im0];
        const float4* x1 = (const float4*)s_p2[im1];
        float a0 = f1b[o], a1 = a0;
        #pragma unroll 8
        for (int k = 0; k < 64; ++k) {
            const float4 w4 = wr[k], p = x0[k], q = x1[k];
            a0 += w4.x * p.x + w4.y * p.y + w4.z * p.z + w4.w * p.w;
            a1 += w4.x * q.x + w4.y * q.y + w4.z * q.z + w4.w * q.w;
        }
        s_f1[im0][o] = fmaxf(a0, 0.f);
        s_f1[im1][o] = fmaxf(a1, 0.f);
    }
    __syncthreads();

    // ---- fc2 (120->84)+relu: task=(o, im-pair), 168 tasks ----
    if (t < 168) {
        const int o = t % 84;
        const int im0 = (t / 84) * 2, im1 = im0 + 1;
        const float4* wr = (const float4*)(f2w + (size_t)o * 120);
        const float4* x0 = (const float4*)s_f1[im0];
        const float4* x1 = (const float4*)s_f1[im1];
        float a0 = f2b[o], a1 = a0;
        #pragma unroll 6
        for (int k = 0; k < 30; ++k) {
            const float4 w4 = wr[k], p = x0[k], q = x1[k];
            a0 += w4.x * p.x + w4.y * p.y + w4.z * p.z + w4.w * p.w;
            a1 += w4.x * q.x + w4.y * q.y + w4.z * q.z + w4.w * q.w;
        }
        s_f2[im0][o] = fmaxf(a0, 0.f);
        s_f2[im1][o] = fmaxf(a1, 0.f);
    }
    __syncthreads();

    // ---- fc3 (84->10): 40 tasks ----
    if (t < 40) {
        const int o = t % 10;
        const int im = t / 10;
        const float4* wr = (const float4*)(f3w + (size_t)o * 84);
        const float4* xr = (const float4*)s_f2[im];
        float a = f3b[o];
        #pragma unroll
        for (int k = 0; k < 21; ++k) {
            const float4 w4 = wr[k], p = xr[k];
            a += w4.x * p.x + w4.y * p.y + w4.z * p.z + w4.w * p.w;
        }
        s_lp[im][o] = a;
    }
    __syncthreads();

    // ---- log_softmax per image ----
    if (t < 4) {
        float mx = -INFINITY;
        #pragma unroll
        for (int i = 0; i < 10; ++i) mx = fmaxf(mx, s_lp[t][i]);
        float sum = 0.f;
        #pragma unroll
        for (int i = 0; i < 10; ++i) sum += expf(s_lp[t][i] - mx);
        const float lse = mx + logf(sum);
        #pragma unroll
        for (int i = 0; i < 10; ++i) s_lp[t][i] -= lse;
    }
    __syncthreads();

    // ---- circuit: per-number log-probs ----
    if (t < NUMS) {
        s_lp1[t] = s_lp[0][t / 10] + s_lp[1][t % 10];
    } else if (t < 2 * NUMS) {
        const int k = t - NUMS;
        s_lp2[k] = s_lp[2][k / 10] + s_lp[3][k % 10];
    }
    __syncthreads();

    // ---- per-segment exact logsumexp over {(i,j): i+j=s} ----
    if (t < SUMS) {
        const int s   = t;
        const int ilo = (s > 99) ? (s - 99) : 0;
        const int ihi = (s < 99) ? s : 99;
        float m = -INFINITY;
        for (int i = ilo; i <= ihi; ++i) m = fmaxf(m, s_lp1[i] + s_lp2[s - i]);
        float sum = 0.f;
        for (int i = ilo; i <= ihi; ++i) sum += expf(s_lp1[i] + s_lp2[s - i] - m);
        out[(size_t)b * SUMS + s] = logf(sum) + m;
    }
}

extern "C" void kernel_launch(void* const* d_in, const int* in_sizes, int n_in,
                              void* d_out, int out_size, void* d_ws, size_t ws_size,
                              hipStream_t stream) {
    const float* images = (const float*)d_in[0];
    const float* c1w = (const float*)d_in[1];
    const float* c1b = (const float*)d_in[2];
    const float* c2w = (const float*)d_in[3];
    const float* c2b = (const float*)d_in[4];
    const float* f1w = (const float*)d_in[5];
    const float* f1b = (const float*)d_in[6];
    const float* f2w = (const float*)d_in[7];
    const float* f2b = (const float*)d_in[8];
    const float* f3w = (const float*)d_in[9];
    const float* f3b = (const float*)d_in[10];
    float* out = (float*)d_out;

    lenet_circuit_kernel<<<BATCH, 256, 0, stream>>>(
        images, c1w, c1b, c2w, c2b, f1w, f1b, f2w, f2b, f3w, f3b, out);
}

// Round 3
// 388.623 us; speedup vs baseline: 1.5748x; 1.1387x over previous
//
#include <hip/hip_runtime.h>
#include <hip/hip_bf16.h>
#include <math.h>

#define NB_DIGITS 2
#define NUMS 100
#define SUMS 199
#define BATCH 4096

typedef __attribute__((ext_vector_type(8))) short short8;   // 8 bf16 (4 VGPRs)
typedef __attribute__((ext_vector_type(4))) float float4v;  // MFMA accumulator

union Frag8 { short8 v; unsigned u[4]; };

static __device__ inline unsigned pk_bf16(float a, float b) {
    __hip_bfloat162 h = __float22bfloat162_rn(make_float2(a, b));
    union { __hip_bfloat162 h; unsigned u; } cvt;
    cvt.h = h;
    return cvt.u;
}

// One workgroup = one batch element (4 digit images), one wave per image.
// conv1/conv2 are bf16 MFMA (16x16x32) implicit GEMMs with LDS gather via a
// k->offset table; pooling via shfl_xor; no barriers between conv1 and conv2
// (same wave produces and consumes). FCs + circuit unchanged (fp32).
__global__ __launch_bounds__(256) void lenet_circuit_kernel(
    const float* __restrict__ images,
    const float* __restrict__ c1w, const float* __restrict__ c1b,
    const float* __restrict__ c2w, const float* __restrict__ c2b,
    const float* __restrict__ f1w, const float* __restrict__ f1b,
    const float* __restrict__ f2w, const float* __restrict__ f2b,
    const float* __restrict__ f3w, const float* __restrict__ f3b,
    float* __restrict__ out)
{
    __shared__ __align__(16) float s_reuse[3136];   // images, later fc buffers
    __shared__ __align__(16) float s_p1[4][864];    // conv1 pooled [6][12*12]
    __shared__ __align__(16) float s_p2[4][256];    // conv2 pooled (fc1 input)
    __shared__ int s_koff2[160];                    // conv2 k -> p1 offset
    __shared__ int s_koff1[32];                     // conv1 k -> img offset

    const int t = threadIdx.x;
    const int b = blockIdx.x;
    const int lane = t & 63;
    const int wav  = t >> 6;        // image index
    const int c    = lane & 15;
    const int h    = lane >> 4;

    // ---- stage images + k-offset tables ----
    {
        const float4* g = (const float4*)(images + (size_t)b * 3136);
        float4* s4 = (float4*)s_reuse;
        for (int i = t; i < 784; i += 256) s4[i] = g[i];
        if (t < 160) {
            int off = 0;
            if (t < 150) { const int ic = t / 25, r = t % 25; off = ic * 144 + (r / 5) * 12 + (r % 5); }
            s_koff2[t] = off;
        } else if (t >= 192 && t < 224) {
            const int k = t - 192;
            s_koff1[k] = (k < 25) ? (k / 5) * 28 + (k % 5) : 0;
        }
    }

    // ---- A-fragments (weights) from global, fp32 -> bf16 ----
    // A[m][k]: m = lane&15, k = (lane>>4)*8 + j
    Frag8 a1;
    {
        float v[8];
        #pragma unroll
        for (int j = 0; j < 8; ++j) {
            const int k = 8 * h + j;
            v[j] = (c < 6 && k < 25) ? c1w[c * 25 + k] : 0.f;
        }
        #pragma unroll
        for (int p = 0; p < 4; ++p) a1.u[p] = pk_bf16(v[2 * p], v[2 * p + 1]);
    }
    Frag8 a2[5];
    #pragma unroll
    for (int s = 0; s < 5; ++s) {
        float v[8];
        #pragma unroll
        for (int j = 0; j < 8; ++j) {
            const int k = 32 * s + 8 * h + j;
            v[j] = (k < 150) ? c2w[c * 150 + k] : 0.f;
        }
        #pragma unroll
        for (int p = 0; p < 4; ++p) a2[s].u[p] = pk_bf16(v[2 * p], v[2 * p + 1]);
    }
    __syncthreads();

    const float* img = s_reuse + wav * 784;
    float*       p1  = s_p1[wav];

    // ---- conv1 (MFMA): per image C[6][576], K=25->32, custom n-order ----
    // tile (qy,qxg): 16 positions = pool quads qx=qxg*4+u (u=c>>2), within-quad
    // bits b0=c&1 (px lsb), b1=(c>>1)&1 (py lsb).
    {
        int ko[8];
        #pragma unroll
        for (int j = 0; j < 8; ++j) ko[j] = s_koff1[8 * h + j];
        const int b0 = c & 1, b1 = (c >> 1) & 1, u = c >> 2;

        for (int qy = 0; qy < 12; ++qy) {
            #pragma unroll
            for (int qxg = 0; qxg < 3; ++qxg) {
                const int qx = qxg * 4 + u;
                const int py = 2 * qy + b1, px = 2 * qx + b0;
                const float* base = img + py * 28 + px;
                float v[8];
                #pragma unroll
                for (int j = 0; j < 8; ++j) v[j] = base[ko[j]];
                Frag8 bf;
                #pragma unroll
                for (int p = 0; p < 4; ++p) bf.u[p] = pk_bf16(v[2 * p], v[2 * p + 1]);
                float4v acc = {0.f, 0.f, 0.f, 0.f};
                acc = __builtin_amdgcn_mfma_f32_16x16x32_bf16(a1.v, bf.v, acc, 0, 0, 0);
                // pool over (b0,b1) partners: lanes c^1, c^2
                #pragma unroll
                for (int r = 0; r < 4; ++r) {
                    float x = acc[r];
                    x = fmaxf(x, __shfl_xor(x, 1));
                    x = fmaxf(x, __shfl_xor(x, 2));
                    const int oc = h * 4 + r;
                    if ((c & 3) == 0 && oc < 6)
                        p1[oc * 144 + qy * 12 + qx] = fmaxf(x + c1b[oc], 0.f);
                }
            }
        }
    }
    // no barrier: conv2 of this wave reads only this wave's p1

    // ---- conv2 (MFMA): C[16][64], K=150->160, n = nt*16+c -> px=c&7, py=(c>>3)+2nt ----
    {
        float4v acc[4];
        #pragma unroll
        for (int nt = 0; nt < 4; ++nt) acc[nt] = (float4v){0.f, 0.f, 0.f, 0.f};

        #pragma unroll
        for (int s = 0; s < 5; ++s) {
            int ko[8];
            #pragma unroll
            for (int j = 0; j < 8; ++j) ko[j] = s_koff2[32 * s + 8 * h + j];
            #pragma unroll
            for (int nt = 0; nt < 4; ++nt) {
                const int px = c & 7, py = (c >> 3) + 2 * nt;
                const float* base = p1 + py * 12 + px;
                float v[8];
                #pragma unroll
                for (int j = 0; j < 8; ++j) v[j] = base[ko[j]];
                Frag8 bf;
                #pragma unroll
                for (int p = 0; p < 4; ++p) bf.u[p] = pk_bf16(v[2 * p], v[2 * p + 1]);
                acc[nt] = __builtin_amdgcn_mfma_f32_16x16x32_bf16(a2[s].v, bf.v, acc[nt], 0, 0, 0);
            }
        }
        float* p2 = s_p2[wav];
        #pragma unroll
        for (int nt = 0; nt < 4; ++nt) {
            #pragma unroll
            for (int r = 0; r < 4; ++r) {
                float x = acc[nt][r];
                x = fmaxf(x, __shfl_xor(x, 1));   // px pair
                x = fmaxf(x, __shfl_xor(x, 8));   // py pair
                if ((c & 9) == 0) {               // c in {0,2,4,6}
                    const int oc = h * 4 + r, qx = c >> 1;
                    p2[oc * 16 + nt * 4 + qx] = fmaxf(x + c2b[oc], 0.f);
                }
            }
        }
    }
    __syncthreads();

    float (*s_f1)[120] = (float (*)[120])(s_reuse);         // 480
    float (*s_f2)[84]  = (float (*)[84])(s_reuse + 480);    // 336
    float (*s_lp)[10]  = (float (*)[10])(s_reuse + 816);    // 40
    float* s_lp1 = s_reuse + 856;                           // 100
    float* s_lp2 = s_reuse + 956;                           // 100

    // ---- fc1 (256->120)+relu: weights read once per image pair ----
    if (t < 240) {
        const int o = t % 120;
        const int im0 = (t / 120) * 2, im1 = im0 + 1;
        const float4* wr = (const float4*)(f1w + (size_t)o * 256);
        const float4* x0 = (const float4*)s_p2[im0];
        const float4* x1 = (const float4*)s_p2[im1];
        float a0 = f1b[o], a1 = a0;
        #pragma unroll 8
        for (int k = 0; k < 64; ++k) {
            const float4 w4 = wr[k], p = x0[k], q = x1[k];
            a0 += w4.x * p.x + w4.y * p.y + w4.z * p.z + w4.w * p.w;
            a1 += w4.x * q.x + w4.y * q.y + w4.z * q.z + w4.w * q.w;
        }
        s_f1[im0][o] = fmaxf(a0, 0.f);
        s_f1[im1][o] = fmaxf(a1, 0.f);
    }
    __syncthreads();

    // ---- fc2 (120->84)+relu ----
    if (t < 168) {
        const int o = t % 84;
        const int im0 = (t / 84) * 2, im1 = im0 + 1;
        const float4* wr = (const float4*)(f2w + (size_t)o * 120);
        const float4* x0 = (const float4*)s_f1[im0];
        const float4* x1 = (const float4*)s_f1[im1];
        float a0 = f2b[o], a1 = a0;
        #pragma unroll 6
        for (int k = 0; k < 30; ++k) {
            const float4 w4 = wr[k], p = x0[k], q = x1[k];
            a0 += w4.x * p.x + w4.y * p.y + w4.z * p.z + w4.w * p.w;
            a1 += w4.x * q.x + w4.y * q.y + w4.z * q.z + w4.w * q.w;
        }
        s_f2[im0][o] = fmaxf(a0, 0.f);
        s_f2[im1][o] = fmaxf(a1, 0.f);
    }
    __syncthreads();

    // ---- fc3 (84->10) ----
    if (t < 40) {
        const int o = t % 10;
        const int im = t / 10;
        const float4* wr = (const float4*)(f3w + (size_t)o * 84);
        const float4* xr = (const float4*)s_f2[im];
        float a = f3b[o];
        #pragma unroll
        for (int k = 0; k < 21; ++k) {
            const float4 w4 = wr[k], p = xr[k];
            a += w4.x * p.x + w4.y * p.y + w4.z * p.z + w4.w * p.w;
        }
        s_lp[im][o] = a;
    }
    __syncthreads();

    // ---- log_softmax per image ----
    if (t < 4) {
        float mx = -INFINITY;
        #pragma unroll
        for (int i = 0; i < 10; ++i) mx = fmaxf(mx, s_lp[t][i]);
        float sum = 0.f;
        #pragma unroll
        for (int i = 0; i < 10; ++i) sum += expf(s_lp[t][i] - mx);
        const float lse = mx + logf(sum);
        #pragma unroll
        for (int i = 0; i < 10; ++i) s_lp[t][i] -= lse;
    }
    __syncthreads();

    // ---- circuit: per-number log-probs ----
    if (t < NUMS) {
        s_lp1[t] = s_lp[0][t / 10] + s_lp[1][t % 10];
    } else if (t < 2 * NUMS) {
        const int k = t - NUMS;
        s_lp2[k] = s_lp[2][k / 10] + s_lp[3][k % 10];
    }
    __syncthreads();

    // ---- per-segment exact logsumexp ----
    if (t < SUMS) {
        const int s   = t;
        const int ilo = (s > 99) ? (s - 99) : 0;
        const int ihi = (s < 99) ? s : 99;
        float m = -INFINITY;
        for (int i = ilo; i <= ihi; ++i) m = fmaxf(m, s_lp1[i] + s_lp2[s - i]);
        float sum = 0.f;
        for (int i = ilo; i <= ihi; ++i) sum += expf(s_lp1[i] + s_lp2[s - i] - m);
        out[(size_t)b * SUMS + s] = logf(sum) + m;
    }
}

extern "C" void kernel_launch(void* const* d_in, const int* in_sizes, int n_in,
                              void* d_out, int out_size, void* d_ws, size_t ws_size,
                              hipStream_t stream) {
    const float* images = (const float*)d_in[0];
    const float* c1w = (const float*)d_in[1];
    const float* c1b = (const float*)d_in[2];
    const float* c2w = (const float*)d_in[3];
    const float* c2b = (const float*)d_in[4];
    const float* f1w = (const float*)d_in[5];
    const float* f1b = (const float*)d_in[6];
    const float* f2w = (const float*)d_in[7];
    const float* f2b = (const float*)d_in[8];
    const float* f3w = (const float*)d_in[9];
    const float* f3b = (const float*)d_in[10];
    float* out = (float*)d_out;

    lenet_circuit_kernel<<<BATCH, 256, 0, stream>>>(
        images, c1w, c1b, c2w, c2b, f1w, f1b, f2w, f2b, f3w, f3b, out);
}